// Round 12
// baseline (77.797 us; speedup 1.0000x reference)
//
#include <hip/hip_runtime.h>

#define CC 512
#define NN 1024
#define NB 8
#define NH 8
#define HD 64

typedef __attribute__((ext_vector_type(8))) short s16x8;
typedef __attribute__((ext_vector_type(4))) short s16x4;
typedef __attribute__((ext_vector_type(4))) float f32x4;
typedef __attribute__((ext_vector_type(16))) float f32x16;

__device__ __forceinline__ unsigned cvtpk(float lo, float hi){
  unsigned r;
  asm("v_cvt_pk_bf16_f32 %0, %1, %2" : "=v"(r) : "v"(lo), "v"(hi));
  return r;
}

__device__ __forceinline__ s16x4 pack4(float a, float b, float c, float d){
  union { unsigned u[2]; s16x4 v; } r;
  r.u[0] = cvtpk(a, b);
  r.u[1] = cvtpk(c, d);
  return r.v;
}

__device__ __forceinline__ void gload16(const void* g, void* l){
  __builtin_amdgcn_global_load_lds((const __attribute__((address_space(1))) void*)g,
                                   (__attribute__((address_space(3))) void*)l, 16, 0, 0);
}

// ---------------- fused: weight fp32->bf16 (blocks 0..1023) + GroupNorm (blocks 1024..1279) ----------------
__global__ __launch_bounds__(256) void prep_kernel(const float* __restrict__ x,
    const float* __restrict__ gsc, const float* __restrict__ gbi,
    const float* __restrict__ w0, const float* __restrict__ w1,
    const float* __restrict__ w2, const float* __restrict__ w3,
    short* __restrict__ wbf, short* __restrict__ xnt){
  if (blockIdx.x < 1024){
    const int i = blockIdx.x*256 + threadIdx.x;
    const int sel = i >> 16;
    const int off = (i & 65535) << 2;
    const float* src = (sel==0) ? w0 : (sel==1) ? w1 : (sel==2) ? w2 : w3;
    const float4 v = *reinterpret_cast<const float4*>(src + off);
    *reinterpret_cast<s16x4*>(wbf + (size_t)sel*262144 + off) = pack4(v.x, v.y, v.z, v.w);
    return;
  }
  const int blk = blockIdx.x - 1024;
  const int b = blk >> 5;
  const int g = blk & 31;
  const int t = threadIdx.x;
  const float* base = x + ((size_t)b*CC + g*16)*NN;
  float4 vals[16];
  float s = 0.f, s2 = 0.f;
  #pragma unroll
  for (int k = 0; k < 16; ++k){
    float4 v = *reinterpret_cast<const float4*>(base + k*NN + t*4);
    vals[k] = v;
    s  += v.x + v.y + v.z + v.w;
    s2 += v.x*v.x + v.y*v.y + v.z*v.z + v.w*v.w;
  }
  #pragma unroll
  for (int m = 1; m < 64; m <<= 1){ s += __shfl_xor(s, m); s2 += __shfl_xor(s2, m); }
  __shared__ float rs[4], rs2[4];
  const int wid = t >> 6, lane = t & 63;
  if (lane == 0){ rs[wid] = s; rs2[wid] = s2; }
  __syncthreads();
  s  = rs[0] + rs[1] + rs[2] + rs[3];
  s2 = rs2[0] + rs2[1] + rs2[2] + rs2[3];
  const float mean = s * (1.f/16384.f);
  const float inv = rsqrtf(s2 * (1.f/16384.f) - mean*mean + 1e-5f);
  float scl[16], off[16];
  #pragma unroll
  for (int k = 0; k < 16; ++k){
    const float sc = gsc[g*16 + k] * inv;
    scl[k] = sc;
    off[k] = gbi[g*16 + k] - mean * sc;
  }
  short* obase = xnt + ((size_t)b*NN + t*4)*CC + g*16;
  #pragma unroll
  for (int i = 0; i < 4; ++i){
    float fv[16];
    #pragma unroll
    for (int k = 0; k < 16; ++k){
      const float v = (i==0) ? vals[k].x : (i==1) ? vals[k].y : (i==2) ? vals[k].z : vals[k].w;
      fv[k] = v * scl[k] + off[k];
    }
    union { unsigned u[4]; s16x8 v; } lo, hi;
    #pragma unroll
    for (int j = 0; j < 4; ++j){
      lo.u[j] = cvtpk(fv[2*j],     fv[2*j + 1]);
      hi.u[j] = cvtpk(fv[8 + 2*j], fv[8 + 2*j + 1]);
    }
    *reinterpret_cast<s16x8*>(obase + (size_t)i*CC)     = lo.v;
    *reinterpret_cast<s16x8*>(obase + (size_t)i*CC + 8) = hi.v;
  }
}

// ---------------- QKV GEMM: Y[o][n] = sum_c W[o][c] * xnt[n][c] ----------------
// 2-phase BK=32 dbuf (32KB), one barrier/K-step, stage-before-compute.
// XCD-locality decode: nt = w&7. 768 blocks.
// z=0 -> Qf frag-tiled (scaled 0.125*log2e); z=1 -> Kf; z=2 -> Vf (swapped ops)
__global__ __launch_bounds__(256) void gemm_qkv(
    const short* __restrict__ Wb, const short* __restrict__ Bmat,
    const float* __restrict__ bias0, const float* __restrict__ bias1, const float* __restrict__ bias2,
    short* __restrict__ qt, short* __restrict__ kt2, short* __restrict__ vo)
{
  const int w = blockIdx.x;
  const int nt = w & 7;
  const int s = w >> 3;
  const int batch = s & 7;
  const int r = s >> 3;
  const int mt = r & 3, z = r >> 2;
  const int tid = threadIdx.x;
  const int lane = tid & 63, wid = tid >> 6;
  const int wm = wid >> 1, wn = wid & 1;

  __shared__ short As[2][128*32];
  __shared__ short Bs[2][128*32];

  const short* Wz = Wb + (size_t)z * 262144;
  const short* Brow = Bmat + ((size_t)batch*NN + nt*128)*CC;

  const f32x4 fzero = {0.f, 0.f, 0.f, 0.f};
  f32x4 acc[4][4];
  #pragma unroll
  for (int i = 0; i < 4; ++i)
  #pragma unroll
  for (int j = 0; j < 4; ++j)
    acc[i][j] = fzero;

  const int srow = tid >> 2, sh = tid & 3;
  const int sg = sh ^ ((srow >> 1) & 3);
  const short* gaBase = Wz + (size_t)(mt*128 + srow)*CC + sg*8;
  const short* gbBase = Brow + (size_t)srow*CC + sg*8;

  auto stage = [&](int kk, int buf){
    const short* ga = gaBase + kk*32;
    const short* gb = gbBase + kk*32;
    gload16(ga,         &As[buf][tid*8]);
    gload16(ga + 64*CC, &As[buf][(tid + 256)*8]);
    gload16(gb,         &Bs[buf][tid*8]);
    gload16(gb + 64*CC, &Bs[buf][(tid + 256)*8]);
  };

  const int rch = (lane >> 4) ^ (((lane & 15) >> 1) & 3);

  auto compute = [&](int buf){
    s16x8 a[4], b[4];
    #pragma unroll
    for (int mi = 0; mi < 4; ++mi){
      const int row = wm*64 + mi*16 + (lane & 15);
      a[mi] = *reinterpret_cast<const s16x8*>(&As[buf][row*32 + rch*8]);
    }
    #pragma unroll
    for (int ni = 0; ni < 4; ++ni){
      const int row = wn*64 + ni*16 + (lane & 15);
      b[ni] = *reinterpret_cast<const s16x8*>(&Bs[buf][row*32 + rch*8]);
    }
    if (z == 2){
      #pragma unroll
      for (int mi = 0; mi < 4; ++mi)
      #pragma unroll
      for (int ni = 0; ni < 4; ++ni)
        acc[mi][ni] = __builtin_amdgcn_mfma_f32_16x16x32_bf16(b[ni], a[mi], acc[mi][ni], 0, 0, 0);
    } else {
      #pragma unroll
      for (int mi = 0; mi < 4; ++mi)
      #pragma unroll
      for (int ni = 0; ni < 4; ++ni)
        acc[mi][ni] = __builtin_amdgcn_mfma_f32_16x16x32_bf16(a[mi], b[ni], acc[mi][ni], 0, 0, 0);
    }
  };

  stage(0, 0);
  asm volatile("s_waitcnt vmcnt(0)" ::: "memory");
  __builtin_amdgcn_s_barrier();
  int buf = 0;
  #pragma unroll
  for (int kk = 0; kk < 16; ++kk){
    if (kk < 15) stage(kk + 1, buf ^ 1);
    compute(buf);
    if (kk < 15){
      asm volatile("s_waitcnt vmcnt(0)" ::: "memory");
      __builtin_amdgcn_s_barrier();
    }
    buf ^= 1;
  }

  const int obase = mt*128 + wm*64;
  const int head = mt*2 + wm;
  const size_t hb = ((size_t)batch*NH + head)*65536;
  const int hi2 = (lane >> 5) & 1;
  const int j0 = ((lane >> 4) & 1)*4;
  if (z < 2){
    const float* bias = (z == 0) ? bias0 : bias1;
    short* dst = (z == 0) ? qt : kt2;
    const float qs = (z == 0) ? 0.125f * 1.44269504f : 1.0f;
    #pragma unroll
    for (int mi = 0; mi < 4; ++mi){
      float bv4[4];
      #pragma unroll
      for (int r2 = 0; r2 < 4; ++r2) bv4[r2] = bias[obase + mi*16 + (lane>>4)*4 + r2];
      #pragma unroll
      for (int ni = 0; ni < 4; ++ni){
        const int l = (ni & 1)*16 + (lane & 15) + 32*hi2;
        const int q5 = nt*4 + wn*2 + (ni >> 1);
        const s16x4 pk = pack4((acc[mi][ni][0] + bv4[0]) * qs,
                               (acc[mi][ni][1] + bv4[1]) * qs,
                               (acc[mi][ni][2] + bv4[2]) * qs,
                               (acc[mi][ni][3] + bv4[3]) * qs);
        *reinterpret_cast<s16x4*>(dst + hb + (size_t)((q5*4 + mi)*64 + l)*8 + j0) = pk;
      }
    }
  } else {
    #pragma unroll
    for (int mi = 0; mi < 4; ++mi){
      const float bv = bias2[obase + mi*16 + (lane & 15)];
      const int ci = mi >> 1;
      const int cl = (mi & 1)*16 + (lane & 15);
      #pragma unroll
      for (int ni = 0; ni < 4; ++ni){
        const int m5 = nt*2 + wn;
        const s16x4 pk = pack4(acc[mi][ni][0] + bv, acc[mi][ni][1] + bv,
                               acc[mi][ni][2] + bv, acc[mi][ni][3] + bv);
        *reinterpret_cast<s16x4*>(vo + hb + (size_t)((((ci*16 + m5)*4 + ni)*64) + cl + 32*hi2)*8 + j0) = pk;
      }
    }
  }
}

// ---------------- proj GEMM (R10 best-known): out f32 (b,c,n) = Wp.aot + bias + resid ----------------
// 128x128 tile, 256 blocks; swapped MFMA (n in regs) -> float4 resid/out I/O.
__global__ __launch_bounds__(256) void gemm_proj(
    const short* __restrict__ Wb, const short* __restrict__ Bmat,
    const float* __restrict__ bias0, const float* __restrict__ resid,
    float* __restrict__ outp)
{
  const int w = blockIdx.x;
  const int nt = w & 7;
  const int s = w >> 3;
  const int batch = s & 7;
  const int mt = s >> 3;
  const int tid = threadIdx.x;
  const int lane = tid & 63, wid = tid >> 6;
  const int wm = wid >> 1, wn = wid & 1;

  __shared__ short As[2][128*32];
  __shared__ short Bs[2][128*32];

  const short* Wz = Wb + (size_t)3 * 262144;
  const short* Brow = Bmat + ((size_t)batch*NN + nt*128)*CC;

  const f32x4 fzero = {0.f, 0.f, 0.f, 0.f};
  f32x4 acc[4][4];
  #pragma unroll
  for (int i = 0; i < 4; ++i)
  #pragma unroll
  for (int j = 0; j < 4; ++j)
    acc[i][j] = fzero;

  const int srow = tid >> 2, sh = tid & 3;
  const int sg = sh ^ ((srow >> 1) & 3);
  const short* gaBase = Wz + (size_t)(mt*128 + srow)*CC + sg*8;
  const short* gbBase = Brow + (size_t)srow*CC + sg*8;

  auto stage = [&](int kk, int buf){
    const short* ga = gaBase + kk*32;
    const short* gb = gbBase + kk*32;
    gload16(ga,         &As[buf][tid*8]);
    gload16(ga + 64*CC, &As[buf][(tid + 256)*8]);
    gload16(gb,         &Bs[buf][tid*8]);
    gload16(gb + 64*CC, &Bs[buf][(tid + 256)*8]);
  };

  const int rch = (lane >> 4) ^ (((lane & 15) >> 1) & 3);

  auto compute = [&](int buf){
    s16x8 a[4], b[4];
    #pragma unroll
    for (int mi = 0; mi < 4; ++mi){
      const int row = wm*64 + mi*16 + (lane & 15);
      a[mi] = *reinterpret_cast<const s16x8*>(&As[buf][row*32 + rch*8]);
    }
    #pragma unroll
    for (int ni = 0; ni < 4; ++ni){
      const int row = wn*64 + ni*16 + (lane & 15);
      b[ni] = *reinterpret_cast<const s16x8*>(&Bs[buf][row*32 + rch*8]);
    }
    #pragma unroll
    for (int mi = 0; mi < 4; ++mi)
    #pragma unroll
    for (int ni = 0; ni < 4; ++ni)
      acc[mi][ni] = __builtin_amdgcn_mfma_f32_16x16x32_bf16(b[ni], a[mi], acc[mi][ni], 0, 0, 0);
  };

  stage(0, 0);
  asm volatile("s_waitcnt vmcnt(0)" ::: "memory");
  __builtin_amdgcn_s_barrier();
  int buf = 0;
  #pragma unroll
  for (int kk = 0; kk < 16; ++kk){
    if (kk < 15) stage(kk + 1, buf ^ 1);
    compute(buf);
    if (kk < 15){
      asm volatile("s_waitcnt vmcnt(0)" ::: "memory");
      __builtin_amdgcn_s_barrier();
    }
    buf ^= 1;
  }

  const int obase = mt*128 + wm*64;
  const int nbase = nt*128 + wn*64;
  #pragma unroll
  for (int mi = 0; mi < 4; ++mi){
    const int o = obase + mi*16 + (lane & 15);
    const float bv = bias0[o];
    #pragma unroll
    for (int ni = 0; ni < 4; ++ni){
      const int n4 = nbase + ni*16 + (lane >> 4)*4;
      const size_t idx = ((size_t)batch*CC + o)*NN + n4;
      const float4 rv = *reinterpret_cast<const float4*>(resid + idx);
      float4 ov;
      ov.x = acc[mi][ni][0] + bv + rv.x;
      ov.y = acc[mi][ni][1] + bv + rv.y;
      ov.z = acc[mi][ni][2] + bv + rv.z;
      ov.w = acc[mi][ni][3] + bv + rv.w;
      *reinterpret_cast<float4*>(outp + idx) = ov;
    }
  }
}

// ---------------- attention: frag-tiled, split-K 2-way, fixed-base softmax, K+V double-buffered ----------------
// 1024 blocks; block = 64 queries x 2 key-halves; wave = 32 queries x 512 keys.
// V prefetched one 64-key tile ahead (like K): loads get PV+next-QK+next-softmax of cover.
__global__ __launch_bounds__(256, 2) void attn_kernel(
    const short* __restrict__ qp, const short* __restrict__ kp, const short* __restrict__ vp,
    short* __restrict__ ot)
{
  const int bid = blockIdx.x;
  const int xcd = bid & 7, rr = bid >> 3;
  const int bh  = xcd*8 + (rr & 7);
  const int qt  = rr >> 3;                    // 0..15
  const int b = bh >> 3, head = bh & 7;
  const int tid = threadIdx.x, lane = tid & 63, wid = tid >> 6;
  const int col = lane & 31;
  const int qg = wid & 1, kh = wid >> 1;
  const int q0 = qt*64 + qg*32;

  const short* Qf = qp + (size_t)bh*65536;
  const short* Kf = kp + (size_t)bh*65536;
  const short* Vf = vp + (size_t)bh*65536;

  __shared__ float Lof[2][32][64];
  __shared__ float Ll[2][64];

  const int q5 = qt*2 + qg;
  s16x8 qf[4];
  #pragma unroll
  for (int ks = 0; ks < 4; ++ks)
    qf[ks] = *reinterpret_cast<const s16x8*>(Qf + (size_t)(q5*4 + ks)*512 + lane*8);

  f32x16 of0, of1;
  #pragma unroll
  for (int r = 0; r < 16; ++r){ of0[r] = 0.f; of1[r] = 0.f; }
  float l = 0.f;

  auto kload = [&](int itn, s16x8 (&kf)[2][4]){
    const short* kb = Kf + (size_t)(kh*16 + itn*2)*2048 + lane*8;
    #pragma unroll
    for (int t = 0; t < 2; ++t)
      #pragma unroll
      for (int ks = 0; ks < 4; ++ks)
        kf[t][ks] = *reinterpret_cast<const s16x8*>(kb + t*2048 + ks*512);
  };

  auto vload = [&](int itn, s16x8 (&vf)[2][4]){
    const short* vb = Vf + (size_t)(kh*8 + itn)*2048 + lane*8;
    #pragma unroll
    for (int ci = 0; ci < 2; ++ci)
      #pragma unroll
      for (int s = 0; s < 4; ++s)
        vf[ci][s] = *reinterpret_cast<const s16x8*>(vb + ci*32768 + s*512);
  };

  auto pack = [&](f32x16& sv, s16x8& p0, s16x8& p1){
    union { unsigned u[4]; s16x8 v; } w0, w1;
    {
      unsigned a = cvtpk(sv[0], sv[1]);
      unsigned c = cvtpk(sv[4], sv[5]);
      auto r = __builtin_amdgcn_permlane32_swap(a, c, false, false);
      w0.u[0] = r[0]; w0.u[2] = r[1];
      a = cvtpk(sv[2], sv[3]);
      c = cvtpk(sv[6], sv[7]);
      r = __builtin_amdgcn_permlane32_swap(a, c, false, false);
      w0.u[1] = r[0]; w0.u[3] = r[1];
    }
    {
      unsigned a = cvtpk(sv[8], sv[9]);
      unsigned c = cvtpk(sv[12], sv[13]);
      auto r = __builtin_amdgcn_permlane32_swap(a, c, false, false);
      w1.u[0] = r[0]; w1.u[2] = r[1];
      a = cvtpk(sv[10], sv[11]);
      c = cvtpk(sv[14], sv[15]);
      r = __builtin_amdgcn_permlane32_swap(a, c, false, false);
      w1.u[1] = r[0]; w1.u[3] = r[1];
    }
    p0 = w0.v; p1 = w1.v;
  };

  auto body = [&](int it, s16x8 (&kf)[2][4], s16x8 (&kfn)[2][4],
                          s16x8 (&vf)[2][4], s16x8 (&vfn)[2][4]){
    f32x16 s0, s1;
    #pragma unroll
    for (int r = 0; r < 16; ++r){ s0[r] = 0.f; s1[r] = 0.f; }
    #pragma unroll
    for (int ks = 0; ks < 4; ++ks){
      s0 = __builtin_amdgcn_mfma_f32_32x32x16_bf16(kf[0][ks], qf[ks], s0, 0, 0, 0);
      s1 = __builtin_amdgcn_mfma_f32_32x32x16_bf16(kf[1][ks], qf[ks], s1, 0, 0, 0);
    }
    if (it < 7) kload(it + 1, kfn);
    #pragma unroll
    for (int r = 0; r < 16; ++r){ s0[r] = __builtin_amdgcn_exp2f(s0[r]); }
    #pragma unroll
    for (int r = 0; r < 16; ++r){ s1[r] = __builtin_amdgcn_exp2f(s1[r]); }
    float t[16];
    #pragma unroll
    for (int r = 0; r < 16; ++r) t[r] = s0[r] + s1[r];
    #pragma unroll
    for (int o = 8; o > 0; o >>= 1)
      #pragma unroll
      for (int r = 0; r < 8; ++r) if (r < o) t[r] = t[r] + t[r + o];
    l += t[0] + __shfl_xor(t[0], 32);
    s16x8 pf[4];
    pack(s0, pf[0], pf[1]);
    pack(s1, pf[2], pf[3]);
    if (it < 7) vload(it + 1, vfn);     // next-tile V in flight across PV + next QK
    #pragma unroll
    for (int s = 0; s < 4; ++s){
      of0 = __builtin_amdgcn_mfma_f32_32x32x16_bf16(vf[0][s], pf[s], of0, 0, 0, 0);
      of1 = __builtin_amdgcn_mfma_f32_32x32x16_bf16(vf[1][s], pf[s], of1, 0, 0, 0);
    }
  };

  s16x8 kfA[2][4], kfB[2][4];
  s16x8 vfA[2][4], vfB[2][4];
  kload(0, kfA);
  vload(0, vfA);
  #pragma unroll 1
  for (int ii = 0; ii < 4; ++ii){
    body(2*ii,     kfA, kfB, vfA, vfB);
    body(2*ii + 1, kfB, kfA, vfB, vfA);
  }

  __syncthreads();
  if (kh == 1){
    #pragma unroll
    for (int r = 0; r < 16; ++r){
      Lof[qg][r][lane]      = of0[r];
      Lof[qg][16 + r][lane] = of1[r];
    }
    Ll[qg][lane] = l;
  }
  __syncthreads();
  if (kh == 0){
    const float linv = 1.f / (l + Ll[qg][lane]);
    const int hi = lane >> 5;
    const int n = q0 + col;
    short* ob = ot + ((size_t)b*NN + n)*CC + head*HD + hi*4;
    #pragma unroll
    for (int rq = 0; rq < 4; ++rq){
      s16x4 pk = pack4((of0[rq*4 + 0] + Lof[qg][rq*4 + 0][lane]) * linv,
                       (of0[rq*4 + 1] + Lof[qg][rq*4 + 1][lane]) * linv,
                       (of0[rq*4 + 2] + Lof[qg][rq*4 + 2][lane]) * linv,
                       (of0[rq*4 + 3] + Lof[qg][rq*4 + 3][lane]) * linv);
      *reinterpret_cast<s16x4*>(ob + rq*8) = pk;
      pk = pack4((of1[rq*4 + 0] + Lof[qg][16 + rq*4 + 0][lane]) * linv,
                 (of1[rq*4 + 1] + Lof[qg][16 + rq*4 + 1][lane]) * linv,
                 (of1[rq*4 + 2] + Lof[qg][16 + rq*4 + 2][lane]) * linv,
                 (of1[rq*4 + 3] + Lof[qg][16 + rq*4 + 3][lane]) * linv);
      *reinterpret_cast<s16x4*>(ob + 32 + rq*8) = pk;
    }
  }
}

extern "C" void kernel_launch(void* const* d_in, const int* in_sizes, int n_in,
                              void* d_out, int out_size, void* d_ws, size_t ws_size,
                              hipStream_t stream) {
  const float* x   = (const float*)d_in[0];
  const float* gsc = (const float*)d_in[1];
  const float* gbi = (const float*)d_in[2];
  const float* wq  = (const float*)d_in[3];
  const float* bq  = (const float*)d_in[4];
  const float* wk  = (const float*)d_in[5];
  const float* bk  = (const float*)d_in[6];
  const float* wv  = (const float*)d_in[7];
  const float* bv  = (const float*)d_in[8];
  const float* wp  = (const float*)d_in[9];
  const float* bp  = (const float*)d_in[10];
  float* out = (float*)d_out;

  char* ws = (char*)d_ws;
  short* wbf = (short*)(ws);                 // 2 MiB: wq,wk,wv,wp bf16
  short* xnt = (short*)(ws + (2u<<20));      // 8 MiB: (b,n,c) bf16
  short* qt  = (short*)(ws + (10u<<20));     // 8 MiB: frag-tiled Q (pre-scaled 0.125*log2e)
  short* kt  = (short*)(ws + (18u<<20));     // 8 MiB: frag-tiled K
  short* v   = (short*)(ws + (26u<<20));     // 8 MiB: frag-tiled V
  short* aot = (short*)(ws + (34u<<20));     // 8 MiB: (b,n,c) bf16

  prep_kernel<<<1280, 256, 0, stream>>>(x, gsc, gbi, wq, wk, wv, wp, wbf, xnt);
  gemm_qkv<<<dim3(768), 256, 0, stream>>>(wbf, xnt, bq, bk, bv, qt, kt, v);
  attn_kernel<<<dim3(1024), 256, 0, stream>>>(qt, kt, v, aot);
  gemm_proj<<<dim3(256), 256, 0, stream>>>(wbf, aot, bp, x, out);
}

// Round 13
// 74.253 us; speedup vs baseline: 1.0477x; 1.0477x over previous
//
#include <hip/hip_runtime.h>

#define CC 512
#define NN 1024
#define NB 8
#define NH 8
#define HD 64

typedef __attribute__((ext_vector_type(8))) short s16x8;
typedef __attribute__((ext_vector_type(4))) short s16x4;
typedef __attribute__((ext_vector_type(4))) float f32x4;
typedef __attribute__((ext_vector_type(16))) float f32x16;

__device__ __forceinline__ unsigned cvtpk(float lo, float hi){
  unsigned r;
  asm("v_cvt_pk_bf16_f32 %0, %1, %2" : "=v"(r) : "v"(lo), "v"(hi));
  return r;
}

__device__ __forceinline__ s16x4 pack4(float a, float b, float c, float d){
  union { unsigned u[2]; s16x4 v; } r;
  r.u[0] = cvtpk(a, b);
  r.u[1] = cvtpk(c, d);
  return r.v;
}

__device__ __forceinline__ void gload16(const void* g, void* l){
  __builtin_amdgcn_global_load_lds((const __attribute__((address_space(1))) void*)g,
                                   (__attribute__((address_space(3))) void*)l, 16, 0, 0);
}

// ---------------- fused: weight fp32->bf16 (blocks 0..1023) + GroupNorm (blocks 1024..1279) ----------------
__global__ __launch_bounds__(256) void prep_kernel(const float* __restrict__ x,
    const float* __restrict__ gsc, const float* __restrict__ gbi,
    const float* __restrict__ w0, const float* __restrict__ w1,
    const float* __restrict__ w2, const float* __restrict__ w3,
    short* __restrict__ wbf, short* __restrict__ xnt){
  if (blockIdx.x < 1024){
    const int i = blockIdx.x*256 + threadIdx.x;
    const int sel = i >> 16;
    const int off = (i & 65535) << 2;
    const float* src = (sel==0) ? w0 : (sel==1) ? w1 : (sel==2) ? w2 : w3;
    const float4 v = *reinterpret_cast<const float4*>(src + off);
    *reinterpret_cast<s16x4*>(wbf + (size_t)sel*262144 + off) = pack4(v.x, v.y, v.z, v.w);
    return;
  }
  const int blk = blockIdx.x - 1024;
  const int b = blk >> 5;
  const int g = blk & 31;
  const int t = threadIdx.x;
  const float* base = x + ((size_t)b*CC + g*16)*NN;
  float4 vals[16];
  float s = 0.f, s2 = 0.f;
  #pragma unroll
  for (int k = 0; k < 16; ++k){
    float4 v = *reinterpret_cast<const float4*>(base + k*NN + t*4);
    vals[k] = v;
    s  += v.x + v.y + v.z + v.w;
    s2 += v.x*v.x + v.y*v.y + v.z*v.z + v.w*v.w;
  }
  #pragma unroll
  for (int m = 1; m < 64; m <<= 1){ s += __shfl_xor(s, m); s2 += __shfl_xor(s2, m); }
  __shared__ float rs[4], rs2[4];
  const int wid = t >> 6, lane = t & 63;
  if (lane == 0){ rs[wid] = s; rs2[wid] = s2; }
  __syncthreads();
  s  = rs[0] + rs[1] + rs[2] + rs[3];
  s2 = rs2[0] + rs2[1] + rs2[2] + rs2[3];
  const float mean = s * (1.f/16384.f);
  const float inv = rsqrtf(s2 * (1.f/16384.f) - mean*mean + 1e-5f);
  float scl[16], off[16];
  #pragma unroll
  for (int k = 0; k < 16; ++k){
    const float sc = gsc[g*16 + k] * inv;
    scl[k] = sc;
    off[k] = gbi[g*16 + k] - mean * sc;
  }
  short* obase = xnt + ((size_t)b*NN + t*4)*CC + g*16;
  #pragma unroll
  for (int i = 0; i < 4; ++i){
    float fv[16];
    #pragma unroll
    for (int k = 0; k < 16; ++k){
      const float v = (i==0) ? vals[k].x : (i==1) ? vals[k].y : (i==2) ? vals[k].z : vals[k].w;
      fv[k] = v * scl[k] + off[k];
    }
    union { unsigned u[4]; s16x8 v; } lo, hi;
    #pragma unroll
    for (int j = 0; j < 4; ++j){
      lo.u[j] = cvtpk(fv[2*j],     fv[2*j + 1]);
      hi.u[j] = cvtpk(fv[8 + 2*j], fv[8 + 2*j + 1]);
    }
    *reinterpret_cast<s16x8*>(obase + (size_t)i*CC)     = lo.v;
    *reinterpret_cast<s16x8*>(obase + (size_t)i*CC + 8) = hi.v;
  }
}

// ---------------- QKV GEMM: Y[o][n] = sum_c W[o][c] * xnt[n][c] ----------------
// 2-phase BK=32 dbuf (32KB), one barrier/K-step, stage-before-compute.
// XCD-locality decode: nt = w&7. 768 blocks.
// z=0 -> Qf frag-tiled (scaled 0.125*log2e); z=1 -> Kf; z=2 -> Vf (swapped ops)
__global__ __launch_bounds__(256) void gemm_qkv(
    const short* __restrict__ Wb, const short* __restrict__ Bmat,
    const float* __restrict__ bias0, const float* __restrict__ bias1, const float* __restrict__ bias2,
    short* __restrict__ qt, short* __restrict__ kt2, short* __restrict__ vo)
{
  const int w = blockIdx.x;
  const int nt = w & 7;
  const int s = w >> 3;
  const int batch = s & 7;
  const int r = s >> 3;
  const int mt = r & 3, z = r >> 2;
  const int tid = threadIdx.x;
  const int lane = tid & 63, wid = tid >> 6;
  const int wm = wid >> 1, wn = wid & 1;

  __shared__ short As[2][128*32];
  __shared__ short Bs[2][128*32];

  const short* Wz = Wb + (size_t)z * 262144;
  const short* Brow = Bmat + ((size_t)batch*NN + nt*128)*CC;

  const f32x4 fzero = {0.f, 0.f, 0.f, 0.f};
  f32x4 acc[4][4];
  #pragma unroll
  for (int i = 0; i < 4; ++i)
  #pragma unroll
  for (int j = 0; j < 4; ++j)
    acc[i][j] = fzero;

  const int srow = tid >> 2, sh = tid & 3;
  const int sg = sh ^ ((srow >> 1) & 3);
  const short* gaBase = Wz + (size_t)(mt*128 + srow)*CC + sg*8;
  const short* gbBase = Brow + (size_t)srow*CC + sg*8;

  auto stage = [&](int kk, int buf){
    const short* ga = gaBase + kk*32;
    const short* gb = gbBase + kk*32;
    gload16(ga,         &As[buf][tid*8]);
    gload16(ga + 64*CC, &As[buf][(tid + 256)*8]);
    gload16(gb,         &Bs[buf][tid*8]);
    gload16(gb + 64*CC, &Bs[buf][(tid + 256)*8]);
  };

  const int rch = (lane >> 4) ^ (((lane & 15) >> 1) & 3);

  auto compute = [&](int buf){
    s16x8 a[4], b[4];
    #pragma unroll
    for (int mi = 0; mi < 4; ++mi){
      const int row = wm*64 + mi*16 + (lane & 15);
      a[mi] = *reinterpret_cast<const s16x8*>(&As[buf][row*32 + rch*8]);
    }
    #pragma unroll
    for (int ni = 0; ni < 4; ++ni){
      const int row = wn*64 + ni*16 + (lane & 15);
      b[ni] = *reinterpret_cast<const s16x8*>(&Bs[buf][row*32 + rch*8]);
    }
    if (z == 2){
      #pragma unroll
      for (int mi = 0; mi < 4; ++mi)
      #pragma unroll
      for (int ni = 0; ni < 4; ++ni)
        acc[mi][ni] = __builtin_amdgcn_mfma_f32_16x16x32_bf16(b[ni], a[mi], acc[mi][ni], 0, 0, 0);
    } else {
      #pragma unroll
      for (int mi = 0; mi < 4; ++mi)
      #pragma unroll
      for (int ni = 0; ni < 4; ++ni)
        acc[mi][ni] = __builtin_amdgcn_mfma_f32_16x16x32_bf16(a[mi], b[ni], acc[mi][ni], 0, 0, 0);
    }
  };

  stage(0, 0);
  asm volatile("s_waitcnt vmcnt(0)" ::: "memory");
  __builtin_amdgcn_s_barrier();
  int buf = 0;
  #pragma unroll
  for (int kk = 0; kk < 16; ++kk){
    if (kk < 15) stage(kk + 1, buf ^ 1);
    compute(buf);
    if (kk < 15){
      asm volatile("s_waitcnt vmcnt(0)" ::: "memory");
      __builtin_amdgcn_s_barrier();
    }
    buf ^= 1;
  }

  const int obase = mt*128 + wm*64;
  const int head = mt*2 + wm;
  const size_t hb = ((size_t)batch*NH + head)*65536;
  const int hi2 = (lane >> 5) & 1;
  const int j0 = ((lane >> 4) & 1)*4;
  if (z < 2){
    const float* bias = (z == 0) ? bias0 : bias1;
    short* dst = (z == 0) ? qt : kt2;
    const float qs = (z == 0) ? 0.125f * 1.44269504f : 1.0f;
    #pragma unroll
    for (int mi = 0; mi < 4; ++mi){
      float bv4[4];
      #pragma unroll
      for (int r2 = 0; r2 < 4; ++r2) bv4[r2] = bias[obase + mi*16 + (lane>>4)*4 + r2];
      #pragma unroll
      for (int ni = 0; ni < 4; ++ni){
        const int l = (ni & 1)*16 + (lane & 15) + 32*hi2;
        const int q5 = nt*4 + wn*2 + (ni >> 1);
        const s16x4 pk = pack4((acc[mi][ni][0] + bv4[0]) * qs,
                               (acc[mi][ni][1] + bv4[1]) * qs,
                               (acc[mi][ni][2] + bv4[2]) * qs,
                               (acc[mi][ni][3] + bv4[3]) * qs);
        *reinterpret_cast<s16x4*>(dst + hb + (size_t)((q5*4 + mi)*64 + l)*8 + j0) = pk;
      }
    }
  } else {
    #pragma unroll
    for (int mi = 0; mi < 4; ++mi){
      const float bv = bias2[obase + mi*16 + (lane & 15)];
      const int ci = mi >> 1;
      const int cl = (mi & 1)*16 + (lane & 15);
      #pragma unroll
      for (int ni = 0; ni < 4; ++ni){
        const int m5 = nt*2 + wn;
        const s16x4 pk = pack4(acc[mi][ni][0] + bv, acc[mi][ni][1] + bv,
                               acc[mi][ni][2] + bv, acc[mi][ni][3] + bv);
        *reinterpret_cast<s16x4*>(vo + hb + (size_t)((((ci*16 + m5)*4 + ni)*64) + cl + 32*hi2)*8 + j0) = pk;
      }
    }
  }
}

// ---------------- proj GEMM: out f32 (b,c,n) = Wp.aot + bias + resid ----------------
// 128x128 tile, 256 blocks; swapped MFMA (n in regs) -> float4 resid/out I/O.
__global__ __launch_bounds__(256) void gemm_proj(
    const short* __restrict__ Wb, const short* __restrict__ Bmat,
    const float* __restrict__ bias0, const float* __restrict__ resid,
    float* __restrict__ outp)
{
  const int w = blockIdx.x;
  const int nt = w & 7;
  const int s = w >> 3;
  const int batch = s & 7;
  const int mt = s >> 3;
  const int tid = threadIdx.x;
  const int lane = tid & 63, wid = tid >> 6;
  const int wm = wid >> 1, wn = wid & 1;

  __shared__ short As[2][128*32];
  __shared__ short Bs[2][128*32];

  const short* Wz = Wb + (size_t)3 * 262144;
  const short* Brow = Bmat + ((size_t)batch*NN + nt*128)*CC;

  const f32x4 fzero = {0.f, 0.f, 0.f, 0.f};
  f32x4 acc[4][4];
  #pragma unroll
  for (int i = 0; i < 4; ++i)
  #pragma unroll
  for (int j = 0; j < 4; ++j)
    acc[i][j] = fzero;

  const int srow = tid >> 2, sh = tid & 3;
  const int sg = sh ^ ((srow >> 1) & 3);
  const short* gaBase = Wz + (size_t)(mt*128 + srow)*CC + sg*8;
  const short* gbBase = Brow + (size_t)srow*CC + sg*8;

  auto stage = [&](int kk, int buf){
    const short* ga = gaBase + kk*32;
    const short* gb = gbBase + kk*32;
    gload16(ga,         &As[buf][tid*8]);
    gload16(ga + 64*CC, &As[buf][(tid + 256)*8]);
    gload16(gb,         &Bs[buf][tid*8]);
    gload16(gb + 64*CC, &Bs[buf][(tid + 256)*8]);
  };

  const int rch = (lane >> 4) ^ (((lane & 15) >> 1) & 3);

  auto compute = [&](int buf){
    s16x8 a[4], b[4];
    #pragma unroll
    for (int mi = 0; mi < 4; ++mi){
      const int row = wm*64 + mi*16 + (lane & 15);
      a[mi] = *reinterpret_cast<const s16x8*>(&As[buf][row*32 + rch*8]);
    }
    #pragma unroll
    for (int ni = 0; ni < 4; ++ni){
      const int row = wn*64 + ni*16 + (lane & 15);
      b[ni] = *reinterpret_cast<const s16x8*>(&Bs[buf][row*32 + rch*8]);
    }
    #pragma unroll
    for (int mi = 0; mi < 4; ++mi)
    #pragma unroll
    for (int ni = 0; ni < 4; ++ni)
      acc[mi][ni] = __builtin_amdgcn_mfma_f32_16x16x32_bf16(b[ni], a[mi], acc[mi][ni], 0, 0, 0);
  };

  stage(0, 0);
  asm volatile("s_waitcnt vmcnt(0)" ::: "memory");
  __builtin_amdgcn_s_barrier();
  int buf = 0;
  #pragma unroll
  for (int kk = 0; kk < 16; ++kk){
    if (kk < 15) stage(kk + 1, buf ^ 1);
    compute(buf);
    if (kk < 15){
      asm volatile("s_waitcnt vmcnt(0)" ::: "memory");
      __builtin_amdgcn_s_barrier();
    }
    buf ^= 1;
  }

  const int obase = mt*128 + wm*64;
  const int nbase = nt*128 + wn*64;
  #pragma unroll
  for (int mi = 0; mi < 4; ++mi){
    const int o = obase + mi*16 + (lane & 15);
    const float bv = bias0[o];
    #pragma unroll
    for (int ni = 0; ni < 4; ++ni){
      const int n4 = nbase + ni*16 + (lane >> 4)*4;
      const size_t idx = ((size_t)batch*CC + o)*NN + n4;
      const float4 rv = *reinterpret_cast<const float4*>(resid + idx);
      float4 ov;
      ov.x = acc[mi][ni][0] + bv + rv.x;
      ov.y = acc[mi][ni][1] + bv + rv.y;
      ov.z = acc[mi][ni][2] + bv + rv.z;
      ov.w = acc[mi][ni][3] + bv + rv.w;
      *reinterpret_cast<float4*>(outp + idx) = ov;
    }
  }
}

// ---------------- attention v2: block-cooperative LDS-staged K/V, full-K, fixed-base softmax ----------------
// 512 blocks = 64 bh x 8 q-tiles(128q); 4 waves x 32 q; 16 iters x 64 keys.
// K/V tile (8KB+8KB) staged ONCE per block per iter via global_load_lds (linear, m104-safe),
// double-buffered (32KB), 2-phase pipeline. 4x less L2 traffic than per-wave loads.
__global__ __launch_bounds__(256, 2) void attn_kernel(
    const short* __restrict__ qp, const short* __restrict__ kp, const short* __restrict__ vp,
    short* __restrict__ ot)
{
  const int bid = blockIdx.x;
  const int xcd = bid & 7, slot = bid >> 3;
  const int bh  = xcd*8 + (slot & 7);          // 8 bh per XCD -> KV 2MB L2-resident
  const int qt  = slot >> 3;                   // 0..7
  const int b = bh >> 3, head = bh & 7;
  const int tid = threadIdx.x, lane = tid & 63, wid = tid >> 6;
  const int col = lane & 31;

  const short* Qf = qp + (size_t)bh*65536;
  const short* Kf = kp + (size_t)bh*65536;
  const short* Vf = vp + (size_t)bh*65536;

  __shared__ short Ks[2][4096];
  __shared__ short Vs[2][4096];

  // Q frags: wave owns 32 queries q5 = qt*4 + wid
  const int q5 = qt*4 + wid;
  s16x8 qf[4];
  #pragma unroll
  for (int ks = 0; ks < 4; ++ks)
    qf[ks] = *reinterpret_cast<const s16x8*>(Qf + (size_t)(q5*4 + ks)*512 + lane*8);

  f32x16 of0, of1;
  #pragma unroll
  for (int r = 0; r < 16; ++r){ of0[r] = 0.f; of1[r] = 0.f; }
  float l = 0.f;

  auto stage = [&](int it, int buf){
    // K tile it: 8KB contiguous at shorts [it*4096, +4096)
    gload16(Kf + (size_t)it*4096 + tid*8,        &Ks[buf][tid*8]);
    gload16(Kf + (size_t)it*4096 + 2048 + tid*8, &Ks[buf][2048 + tid*8]);
    // V tile it: two 4KB chunks at (it)*2048 and (16+it)*2048
    gload16(Vf + (size_t)it*2048 + tid*8,        &Vs[buf][tid*8]);
    gload16(Vf + (size_t)(16 + it)*2048 + tid*8, &Vs[buf][2048 + tid*8]);
  };

  auto pack = [&](f32x16& sv, s16x8& p0, s16x8& p1){
    union { unsigned u[4]; s16x8 v; } w0, w1;
    {
      unsigned a = cvtpk(sv[0], sv[1]);
      unsigned c = cvtpk(sv[4], sv[5]);
      auto r = __builtin_amdgcn_permlane32_swap(a, c, false, false);
      w0.u[0] = r[0]; w0.u[2] = r[1];
      a = cvtpk(sv[2], sv[3]);
      c = cvtpk(sv[6], sv[7]);
      r = __builtin_amdgcn_permlane32_swap(a, c, false, false);
      w0.u[1] = r[0]; w0.u[3] = r[1];
    }
    {
      unsigned a = cvtpk(sv[8], sv[9]);
      unsigned c = cvtpk(sv[12], sv[13]);
      auto r = __builtin_amdgcn_permlane32_swap(a, c, false, false);
      w1.u[0] = r[0]; w1.u[2] = r[1];
      a = cvtpk(sv[10], sv[11]);
      c = cvtpk(sv[14], sv[15]);
      r = __builtin_amdgcn_permlane32_swap(a, c, false, false);
      w1.u[1] = r[0]; w1.u[3] = r[1];
    }
    p0 = w0.v; p1 = w1.v;
  };

  auto body = [&](int it, int buf){
    // K frags from LDS (conflict-free contiguous b128)
    s16x8 kf[2][4];
    #pragma unroll
    for (int t = 0; t < 2; ++t)
      #pragma unroll
      for (int ks = 0; ks < 4; ++ks)
        kf[t][ks] = *reinterpret_cast<const s16x8*>(&Ks[buf][t*2048 + ks*512 + lane*8]);
    if (it < 15) stage(it + 1, buf ^ 1);       // DMA flies under compute
    f32x16 s0, s1;
    #pragma unroll
    for (int r = 0; r < 16; ++r){ s0[r] = 0.f; s1[r] = 0.f; }
    #pragma unroll
    for (int ks = 0; ks < 4; ++ks){
      s0 = __builtin_amdgcn_mfma_f32_32x32x16_bf16(kf[0][ks], qf[ks], s0, 0, 0, 0);
      s1 = __builtin_amdgcn_mfma_f32_32x32x16_bf16(kf[1][ks], qf[ks], s1, 0, 0, 0);
    }
    #pragma unroll
    for (int r = 0; r < 16; ++r){ s0[r] = __builtin_amdgcn_exp2f(s0[r]); }
    #pragma unroll
    for (int r = 0; r < 16; ++r){ s1[r] = __builtin_amdgcn_exp2f(s1[r]); }
    float t[16];
    #pragma unroll
    for (int r = 0; r < 16; ++r) t[r] = s0[r] + s1[r];
    #pragma unroll
    for (int o = 8; o > 0; o >>= 1)
      #pragma unroll
      for (int r = 0; r < 8; ++r) if (r < o) t[r] = t[r] + t[r + o];
    l += t[0] + __shfl_xor(t[0], 32);
    s16x8 pf[4];
    pack(s0, pf[0], pf[1]);
    pack(s1, pf[2], pf[3]);
    // V frags from LDS
    s16x8 vf[2][4];
    #pragma unroll
    for (int ci = 0; ci < 2; ++ci)
      #pragma unroll
      for (int s = 0; s < 4; ++s)
        vf[ci][s] = *reinterpret_cast<const s16x8*>(&Vs[buf][ci*2048 + s*512 + lane*8]);
    #pragma unroll
    for (int s = 0; s < 4; ++s){
      of0 = __builtin_amdgcn_mfma_f32_32x32x16_bf16(vf[0][s], pf[s], of0, 0, 0, 0);
      of1 = __builtin_amdgcn_mfma_f32_32x32x16_bf16(vf[1][s], pf[s], of1, 0, 0, 0);
    }
    if (it < 15){
      __builtin_amdgcn_sched_barrier(0);       // pin MFMAs (and their lgkm waits) before the barrier
      asm volatile("s_waitcnt vmcnt(0)" ::: "memory");
      __builtin_amdgcn_s_barrier();            // next tile landed; this buf free for overwrite
    }
  };

  stage(0, 0);
  asm volatile("s_waitcnt vmcnt(0)" ::: "memory");
  __builtin_amdgcn_s_barrier();
  #pragma unroll 1
  for (int ii = 0; ii < 8; ++ii){
    body(2*ii,     0);
    body(2*ii + 1, 1);
  }

  // normalize + store (b, n, c)
  const float linv = 1.f / l;
  const int hi = lane >> 5;
  const int n = qt*128 + wid*32 + col;
  short* ob = ot + ((size_t)b*NN + n)*CC + head*HD + hi*4;
  #pragma unroll
  for (int rq = 0; rq < 4; ++rq){
    s16x4 pk = pack4(of0[rq*4 + 0] * linv, of0[rq*4 + 1] * linv,
                     of0[rq*4 + 2] * linv, of0[rq*4 + 3] * linv);
    *reinterpret_cast<s16x4*>(ob + rq*8) = pk;
    pk = pack4(of1[rq*4 + 0] * linv, of1[rq*4 + 1] * linv,
               of1[rq*4 + 2] * linv, of1[rq*4 + 3] * linv);
    *reinterpret_cast<s16x4*>(ob + 32 + rq*8) = pk;
  }
}

extern "C" void kernel_launch(void* const* d_in, const int* in_sizes, int n_in,
                              void* d_out, int out_size, void* d_ws, size_t ws_size,
                              hipStream_t stream) {
  const float* x   = (const float*)d_in[0];
  const float* gsc = (const float*)d_in[1];
  const float* gbi = (const float*)d_in[2];
  const float* wq  = (const float*)d_in[3];
  const float* bq  = (const float*)d_in[4];
  const float* wk  = (const float*)d_in[5];
  const float* bk  = (const float*)d_in[6];
  const float* wv  = (const float*)d_in[7];
  const float* bv  = (const float*)d_in[8];
  const float* wp  = (const float*)d_in[9];
  const float* bp  = (const float*)d_in[10];
  float* out = (float*)d_out;

  char* ws = (char*)d_ws;
  short* wbf = (short*)(ws);                 // 2 MiB: wq,wk,wv,wp bf16
  short* xnt = (short*)(ws + (2u<<20));      // 8 MiB: (b,n,c) bf16
  short* qt  = (short*)(ws + (10u<<20));     // 8 MiB: frag-tiled Q (pre-scaled 0.125*log2e)
  short* kt  = (short*)(ws + (18u<<20));     // 8 MiB: frag-tiled K
  short* v   = (short*)(ws + (26u<<20));     // 8 MiB: frag-tiled V
  short* aot = (short*)(ws + (34u<<20));     // 8 MiB: (b,n,c) bf16

  prep_kernel<<<1280, 256, 0, stream>>>(x, gsc, gbi, wq, wk, wv, wp, wbf, xnt);
  gemm_qkv<<<dim3(768), 256, 0, stream>>>(wbf, xnt, bq, bk, bv, qt, kt, v);
  attn_kernel<<<dim3(512), 256, 0, stream>>>(qt, kt, v, aot);
  gemm_proj<<<dim3(256), 256, 0, stream>>>(wbf, aot, bp, x, out);
}